// Round 12
// baseline (248.950 us; speedup 1.0000x reference)
//
#include <hip/hip_runtime.h>
#include <math.h>

#define AS1 __attribute__((address_space(1)))
#define AS3 __attribute__((address_space(3)))

typedef __attribute__((ext_vector_type(8))) short short8;
typedef __attribute__((ext_vector_type(8))) unsigned short ushort8_t;
typedef __attribute__((ext_vector_type(4))) float f32x4;

#define WAITV(n) asm volatile("s_waitcnt vmcnt(" #n ")" ::: "memory")
#define BARRIER() asm volatile("s_barrier" ::: "memory")

static __device__ __forceinline__ unsigned short f2bf(float f) {
    unsigned u = __float_as_uint(f);
    unsigned r = (u + 0x7fffu + ((u >> 16) & 1u)) >> 16;
    return (unsigned short)r;
}
static __device__ __forceinline__ float bf2f(unsigned short u) {
    return __uint_as_float(((unsigned)u) << 16);
}

// ---------------- fused f32 -> bf16 convert for all 5 tensors ----------------
__global__ __launch_bounds__(256)
void cvt_all(const float* __restrict__ s0, unsigned short* __restrict__ d0, int n0,
             const float* __restrict__ s1, unsigned short* __restrict__ d1, int n1,
             const float* __restrict__ s2, unsigned short* __restrict__ d2, int n2,
             const float* __restrict__ s3, unsigned short* __restrict__ d3, int n3,
             const float* __restrict__ s4, unsigned short* __restrict__ d4, int n4c) {
    int i = blockIdx.x * 256 + threadIdx.x;
    int stride = gridDim.x * 256;
    int t01 = n0 + n1, t02 = t01 + n2, t03 = t02 + n3, tot = t03 + n4c;
    for (; i < tot; i += stride) {
        const float* s; unsigned short* d; int j;
        if (i < n0)      { s = s0; d = d0; j = i; }
        else if (i < t01){ s = s1; d = d1; j = i - n0; }
        else if (i < t02){ s = s2; d = d2; j = i - t01; }
        else if (i < t03){ s = s3; d = d3; j = i - t02; }
        else             { s = s4; d = d4; j = i - t03; }
        float4 v = ((const float4*)s)[j];
        ushort4 o;
        o.x = f2bf(v.x); o.y = f2bf(v.y); o.z = f2bf(v.z); o.w = f2bf(v.w);
        ((ushort4*)d)[j] = o;
    }
}

// extract ts (cols 0..127 of ssm_p, row stride 160) -> dense bf16 1024x128
__global__ __launch_bounds__(256) void cvt_ts(const float* __restrict__ ssmp,
                                              unsigned short* __restrict__ ts) {
    int i = blockIdx.x * 256 + threadIdx.x;   // < 32768
    int t = i >> 5, c4 = (i & 31) * 4;
    float4 v = *(const float4*)&ssmp[t * 160 + c4];
    ushort4 o;
    o.x = f2bf(v.x); o.y = f2bf(v.y); o.z = f2bf(v.z); o.w = f2bf(v.w);
    *(ushort4*)&ts[t * 128 + c4] = o;
}

// ------- depthwise causal conv (K=4, bf16 in) + bias + silu -> hc bf16 -------
__global__ __launch_bounds__(256) void conv_silu(const unsigned short* __restrict__ h,
                                                 const float* __restrict__ cw,
                                                 const float* __restrict__ cb,
                                                 unsigned short* __restrict__ hc_bf) {
    int idx = blockIdx.x * 256 + threadIdx.x;   // < 1024*4096
    int d = idx & 4095, t = idx >> 12;
    float acc = cb[d];
    float4 w = *(const float4*)&cw[d * 4];
    const float* wp = (const float*)&w;
#pragma unroll
    for (int k = 0; k < 4; ++k) {
        int tt = t + k - 3;
        if (tt >= 0) acc += bf2f(h[tt * 4096 + d]) * wp[k];
    }
    float s = acc / (1.f + __expf(-acc));   // silu
    hc_bf[idx] = f2bf(s);
}

// ---- reduce 2 bf16 split-K partials (1024x8192) -> h bf16 | silu(gate) bf16 ----
__global__ __launch_bounds__(256) void reduce2(const unsigned short* __restrict__ P,
                                               unsigned short* __restrict__ h_bf,
                                               unsigned short* __restrict__ gate_bf) {
    const int NCHK = 1024 * 8192 / 8;
    int i = blockIdx.x * 256 + threadIdx.x;
    int stride = gridDim.x * 256;
    for (; i < NCHK; i += stride) {
        ushort8_t a = ((const ushort8_t*)P)[i];
        ushort8_t b = ((const ushort8_t*)P)[i + NCHK];
        int e0 = i * 8;
        int row = e0 >> 13, col = e0 & 8191;
        ushort8_t o;
        if (col < 4096) {
#pragma unroll
            for (int j = 0; j < 8; ++j) o[j] = f2bf(bf2f(a[j]) + bf2f(b[j]));
            ((ushort8_t*)h_bf)[(row * 4096 + col) >> 3] = o;
        } else {
#pragma unroll
            for (int j = 0; j < 8; ++j) {
                float v = bf2f(a[j]) + bf2f(b[j]);
                o[j] = f2bf(v / (1.f + __expf(-v)));
            }
            ((ushort8_t*)gate_bf)[(row * 4096 + (col - 4096)) >> 3] = o;
        }
    }
}

// ---- reduce 8 bf16 split-K partials (1024x2048 each) -> f32 out ----
__global__ __launch_bounds__(256) void reduce8(const unsigned short* __restrict__ P,
                                               float* __restrict__ out) {
    const int NCHK = 1024 * 2048 / 4;
    int i = blockIdx.x * 256 + threadIdx.x;
    int stride = gridDim.x * 256;
    for (; i < NCHK; i += stride) {
        float4 s = make_float4(0.f, 0.f, 0.f, 0.f);
#pragma unroll
        for (int z = 0; z < 8; ++z) {
            ushort4 v = ((const ushort4*)(P + (size_t)z * 1024 * 2048))[i];
            s.x += bf2f(v.x); s.y += bf2f(v.y); s.z += bf2f(v.z); s.w += bf2f(v.w);
        }
        ((float4*)out)[i] = s;
    }
}

// ======== 256x256 quadrant-phase bf16 MFMA GEMM: C = A(M,K) @ B(N,K)^T ========
// BM=BN=256, BK=32. 512 threads = 8 waves (2M x 4N), wave tile 128x64.
// 3-buffer LDS (96KB), prefetch depth 2, counted vmcnt(4), 2 quadrant-phases
// per K-tile, slot-XOR swizzle (round-11: conflicts 0). Round-12: K-loop
// manually 3x-unrolled so the LDS buffer base is a COMPILE-TIME constant
// (ds_read immediate offsets), and all read offsets / staging source
// pointers hoisted out of the loop (in-loop = 4 pointer bumps) — attacks
// the ~450cyc/tile VALU address overhead (VALUBusy 17% at round 11).
// XCD-bijective block swizzle. Split-K bf16 partials -> reduce2/reduce8.
__global__ __launch_bounds__(512, 2)
void gemm256p(const short* __restrict__ A, const short* __restrict__ B,
              unsigned short* __restrict__ Pbase,
              int N, int K, int kchunk) {
    __shared__ short lds[3 * 16384];   // per buf: A [256][32] (8192) + B [256][32]

    const int tid = threadIdx.x;
    const int wv = tid >> 6, ln = tid & 63;
    const int lr = ln & 15, kg = ln >> 4;
    const int wm = wv >> 2, wn = wv & 3;      // 2M x 4N

    const int nwg = gridDim.x;                 // multiple of 8
    const int bid = blockIdx.x;
    const int swz = (bid & 7) * (nwg >> 3) + (bid >> 3);
    const int by = swz & 3, bx = swz >> 2;     // M/256 = 4 always
    const int m0 = by * 256, n0 = bx * 256;
    const int kbeg = blockIdx.z * kchunk;
    const int NT = kchunk >> 5;                // BK = 32

    f32x4 acc[8][4];
#pragma unroll
    for (int mi = 0; mi < 8; ++mi)
#pragma unroll
        for (int ni = 0; ni < 4; ++ni) acc[mi][ni] = (f32x4){0.f, 0.f, 0.f, 0.f};

    // ---- hoisted staging state (round-12) ----
    // 4 global sources per thread (A pass0/1, B pass0/1), advance +32/tile.
    // Source slot pre-swizzled: LDS slot s of row r holds Global slot
    // s ^ ((r>>1)&3)  (both-sides swizzle, rule 21).
    const short *sA0, *sA1, *sB0, *sB1;
    {
        int c0 = tid,        r0 = c0 >> 2, ss0 = (c0 & 3) ^ ((r0 >> 1) & 3);
        int c1 = 512 + tid,  r1 = c1 >> 2, ss1 = (c1 & 3) ^ ((r1 >> 1) & 3);
        sA0 = A + (size_t)(m0 + r0) * K + kbeg + ss0 * 8;
        sA1 = A + (size_t)(m0 + r1) * K + kbeg + ss1 * 8;
        sB0 = B + (size_t)(n0 + r0) * K + kbeg + ss0 * 8;
        sB1 = B + (size_t)(n0 + r1) * K + kbeg + ss1 * 8;
    }
    // wave-uniform LDS dest offsets (shorts); HW adds lane*16B
    const int dA0 = wv * 512;
    const int dA1 = 4096 + wv * 512;
    const int dB0 = 8192 + wv * 512;
    const int dB1 = 12288 + wv * 512;
    // hoisted fragment read offsets (shorts, incl. swizzle XOR)
    int roA[8], roB[4];
#pragma unroll
    for (int mi = 0; mi < 8; ++mi) {
        int row = wm * 128 + mi * 16 + lr;
        roA[mi] = row * 32 + (kg ^ ((row >> 1) & 3)) * 8;
    }
#pragma unroll
    for (int ni = 0; ni < 4; ++ni) {
        int row = wn * 64 + ni * 16 + lr;
        roB[ni] = 8192 + row * 32 + (kg ^ ((row >> 1) & 3)) * 8;
    }

#define STAGE_A(BB)                                                           \
    { __builtin_amdgcn_global_load_lds((const AS1 void*)sA0,                  \
          (AS3 void*)(lds + (BB) * 16384 + dA0), 16, 0, 0);                   \
      __builtin_amdgcn_global_load_lds((const AS1 void*)sA1,                  \
          (AS3 void*)(lds + (BB) * 16384 + dA1), 16, 0, 0);                   \
      sA0 += 32; sA1 += 32; }
#define STAGE_B(BB)                                                           \
    { __builtin_amdgcn_global_load_lds((const AS1 void*)sB0,                  \
          (AS3 void*)(lds + (BB) * 16384 + dB0), 16, 0, 0);                   \
      __builtin_amdgcn_global_load_lds((const AS1 void*)sB1,                  \
          (AS3 void*)(lds + (BB) * 16384 + dB1), 16, 0, 0);                   \
      sB0 += 32; sB1 += 32; }
#define MFMA4(mi, a)                                                          \
    acc[mi][0] = __builtin_amdgcn_mfma_f32_16x16x32_bf16(a, vb0, acc[mi][0], 0, 0, 0); \
    acc[mi][1] = __builtin_amdgcn_mfma_f32_16x16x32_bf16(a, vb1, acc[mi][1], 0, 0, 0); \
    acc[mi][2] = __builtin_amdgcn_mfma_f32_16x16x32_bf16(a, vb2, acc[mi][2], 0, 0, 0); \
    acc[mi][3] = __builtin_amdgcn_mfma_f32_16x16x32_bf16(a, vb3, acc[mi][3], 0, 0, 0);

// one K-tile with compile-time buffer base BB; stages tile kt+2 into BN2
#define BODY(BB, BN2, ktv)                                                    \
    {                                                                         \
        if ((ktv) + 1 < NT) { WAITV(4); } else { WAITV(0); }                  \
        BARRIER();                                                            \
        const bool pf_ = (ktv) + 2 < NT;                                      \
        if (pf_) STAGE_A(BN2);                                                \
        const short* la = lds + (BB) * 16384;                                 \
        short8 va0, va1, va2, va3, vb0, vb1, vb2, vb3;                        \
        vb0 = *(const short8*)(la + roB[0]);                                  \
        vb1 = *(const short8*)(la + roB[1]);                                  \
        vb2 = *(const short8*)(la + roB[2]);                                  \
        vb3 = *(const short8*)(la + roB[3]);                                  \
        va0 = *(const short8*)(la + roA[0]);                                  \
        va1 = *(const short8*)(la + roA[1]);                                  \
        va2 = *(const short8*)(la + roA[2]);                                  \
        va3 = *(const short8*)(la + roA[3]);                                  \
        __builtin_amdgcn_s_setprio(1);                                        \
        MFMA4(0, va0); MFMA4(1, va1); MFMA4(2, va2); MFMA4(3, va3);           \
        __builtin_amdgcn_s_setprio(0);                                        \
        BARRIER();                                                            \
        if (pf_) STAGE_B(BN2);                                                \
        va0 = *(const short8*)(la + roA[4]);                                  \
        va1 = *(const short8*)(la + roA[5]);                                  \
        va2 = *(const short8*)(la + roA[6]);                                  \
        va3 = *(const short8*)(la + roA[7]);                                  \
        __builtin_amdgcn_s_setprio(1);                                        \
        MFMA4(4, va0); MFMA4(5, va1); MFMA4(6, va2); MFMA4(7, va3);           \
        __builtin_amdgcn_s_setprio(0);                                        \
    }

    // prologue: stage tiles 0 and 1 fully
    STAGE_A(0); STAGE_B(0);
    STAGE_A(1); STAGE_B(1);

    int kt = 0;
    for (; kt + 3 <= NT; kt += 3) {   // buffers cycle 0,1,2 aligned with kt%3
        BODY(0, 2, kt);
        BODY(1, 0, kt + 1);
        BODY(2, 1, kt + 2);
    }
    for (; kt < NT; ++kt) {           // tail (NT%3 iterations, no staging left)
        int bb = kt % 3;
        if (bb == 0)      BODY(0, 2, kt)
        else if (bb == 1) BODY(1, 0, kt)
        else              BODY(2, 1, kt)
    }
#undef STAGE_A
#undef STAGE_B
#undef MFMA4
#undef BODY

    // epilogue: bf16 split-K partial, region z = blockIdx.z
    unsigned short* P = Pbase + (size_t)blockIdx.z * 1024 * N;
#pragma unroll
    for (int mi = 0; mi < 8; ++mi) {
        int crow0 = m0 + wm * 128 + mi * 16 + kg * 4;
#pragma unroll
        for (int ni = 0; ni < 4; ++ni) {
            int ccol = n0 + wn * 64 + ni * 16 + lr;
#pragma unroll
            for (int i = 0; i < 4; ++i)
                P[(size_t)(crow0 + i) * N + ccol] = f2bf(acc[mi][ni][i]);
        }
    }
}

// ---------------- 2-phase bf16 MFMA GEMM (GEMM2/3) ----------------
enum { EPI_PLAIN = 0, EPI_SPLIT = 1, EPI_ATOMIC = 2, EPI_SOFTPLUS = 3 };

template <int BM, int EPI>
__global__ __launch_bounds__(256)
void gemm_bt(const short* __restrict__ A, const short* __restrict__ B,
             float* __restrict__ C, float* __restrict__ C2,
             const float* __restrict__ bias,
             int M, int N, int K, int ldc, int kcLen) {
    __shared__ short A_lds[BM * 32];
    __shared__ short B_lds[128 * 32];
    const int tid = threadIdx.x;
    const int wv = tid >> 6, ln = tid & 63;
    const int lr = ln & 15, kg = ln >> 4;
    const int m0 = blockIdx.y * BM;
    const int n0 = blockIdx.x * 128;
    const int kbeg = blockIdx.z * kcLen;
    const int kend = kbeg + kcLen;
    const int wm = wv >> 1, wn = wv & 1;
    constexpr int MR = BM / 32;

    f32x4 acc[MR][4];
#pragma unroll
    for (int mi = 0; mi < MR; ++mi)
#pragma unroll
        for (int ni = 0; ni < 4; ++ni) acc[mi][ni] = (f32x4){0.f, 0.f, 0.f, 0.f};

    const int arow = tid >> 2;
    const int kq8 = (tid & 3) * 8;

    for (int k0 = kbeg; k0 < kend; k0 += 32) {
#pragma unroll
        for (int r = 0; r < BM / 64; ++r) {
            const short* srcA = A + (size_t)(m0 + r * 64 + arow) * K + (k0 + kq8);
            short* dstA = &A_lds[(r * 64 + wv * 16) * 32];
            __builtin_amdgcn_global_load_lds((const AS1 void*)srcA, (AS3 void*)dstA, 16, 0, 0);
        }
#pragma unroll
        for (int r = 0; r < 2; ++r) {
            int brow = n0 + r * 64 + arow;
            if (brow > N - 1) brow = N - 1;
            const short* srcB = B + (size_t)brow * K + (k0 + kq8);
            short* dstB = &B_lds[(r * 64 + wv * 16) * 32];
            __builtin_amdgcn_global_load_lds((const AS1 void*)srcB, (AS3 void*)dstB, 16, 0, 0);
        }
        __syncthreads();

        short8 av[MR], bv[4];
#pragma unroll
        for (int mi = 0; mi < MR; ++mi)
            av[mi] = *(const short8*)&A_lds[(wm * (BM / 2) + mi * 16 + lr) * 32 + kg * 8];
#pragma unroll
        for (int ni = 0; ni < 4; ++ni)
            bv[ni] = *(const short8*)&B_lds[(wn * 64 + ni * 16 + lr) * 32 + kg * 8];
#pragma unroll
        for (int mi = 0; mi < MR; ++mi)
#pragma unroll
            for (int ni = 0; ni < 4; ++ni)
                acc[mi][ni] = __builtin_amdgcn_mfma_f32_16x16x32_bf16(av[mi], bv[ni], acc[mi][ni], 0, 0, 0);
        __syncthreads();
    }

#pragma unroll
    for (int mi = 0; mi < MR; ++mi) {
        int crow0 = m0 + wm * (BM / 2) + mi * 16 + kg * 4;
#pragma unroll
        for (int ni = 0; ni < 4; ++ni) {
            int ccol = n0 + wn * 64 + ni * 16 + lr;
#pragma unroll
            for (int i = 0; i < 4; ++i) {
                float v = acc[mi][ni][i];
                size_t crow = (size_t)(crow0 + i);
                if constexpr (EPI == EPI_PLAIN) {
                    C[crow * ldc + ccol] = v;
                } else if constexpr (EPI == EPI_SPLIT) {
                    if (ccol < 4096) C[crow * 4096 + ccol] = v;
                    else C2[crow * 4096 + (ccol - 4096)] = v;
                } else if constexpr (EPI == EPI_ATOMIC) {
                    if (ccol < N) atomicAdd(&C[crow * ldc + ccol], v);
                } else {   // EPI_SOFTPLUS: bf16 softplus(v + bias[n]) -> dt
                    float x = v + bias[ccol];
                    float sp = fmaxf(x, 0.f) + log1pf(__expf(-fabsf(x)));
                    ((unsigned short*)C)[crow * ldc + ccol] = f2bf(sp);
                }
            }
        }
    }
}

// ================= chunked selective scan (bf16 dt/hc/gate) =================
#define CLEN 16
#define NCH 64

__global__ __launch_bounds__(256)
void scan_p1(const unsigned short* __restrict__ dt, const unsigned short* __restrict__ hc,
             const float* __restrict__ ssmp, const float* __restrict__ A_log,
             float* __restrict__ Sbuf, float* __restrict__ dtsum) {
    const int tid = threadIdx.x;
    const int c = blockIdx.x & (NCH - 1);
    const int db = blockIdx.x >> 6;
    const int d = db * 256 + tid;
    const int t0 = c * CLEN;

    float Ac[16];
#pragma unroll
    for (int i = 0; i < 4; ++i) {
        float4 v = *(const float4*)&A_log[d * 16 + i * 4];
        Ac[i*4+0] = -__expf(v.x); Ac[i*4+1] = -__expf(v.y);
        Ac[i*4+2] = -__expf(v.z); Ac[i*4+3] = -__expf(v.w);
    }

    __shared__ float sB[CLEN][16];
    sB[tid >> 4][tid & 15] = ssmp[(t0 + (tid >> 4)) * 160 + 128 + (tid & 15)];
    __syncthreads();

    float st[16];
#pragma unroll
    for (int n = 0; n < 16; ++n) st[n] = 0.f;
    float ds = 0.f;

    for (int tt = 0; tt < CLEN; ++tt) {
        size_t g = (size_t)(t0 + tt) * 4096 + d;
        float dtv = bf2f(dt[g]);
        float hcv = bf2f(hc[g]);
        float du = dtv * hcv;
        ds += dtv;
#pragma unroll
        for (int n = 0; n < 16; ++n) {
            float dA = __expf(dtv * Ac[n]);
            st[n] = fmaf(dA, st[n], du * sB[tt][n]);
        }
    }

    float* o = Sbuf + ((size_t)c * 4096 + d) * 16;
#pragma unroll
    for (int i = 0; i < 4; ++i)
        *(float4*)&o[i * 4] = make_float4(st[i*4], st[i*4+1], st[i*4+2], st[i*4+3]);
    dtsum[c * 4096 + d] = ds;
}

__global__ __launch_bounds__(256)
void scan_p2(const float* __restrict__ A_log, const float* __restrict__ dtsum,
             float* __restrict__ S) {
    const int idx = blockIdx.x * 256 + threadIdx.x;   // (d,n), 65536
    const int d = idx >> 4;
    const float Ac = -__expf(A_log[idx]);

    float sl[NCH], Pv[NCH];
#pragma unroll
    for (int c = 0; c < NCH; ++c) sl[c] = S[(size_t)c * 65536 + idx];
#pragma unroll
    for (int c = 0; c < NCH; ++c) Pv[c] = __expf(Ac * dtsum[c * 4096 + d]);

    float s = 0.f;
#pragma unroll
    for (int c = 0; c < NCH; ++c) {
        S[(size_t)c * 65536 + idx] = s;
        s = fmaf(Pv[c], s, sl[c]);
    }
}

__global__ __launch_bounds__(256)
void scan_p3(const unsigned short* __restrict__ dt, const unsigned short* __restrict__ hc,
             const float* __restrict__ ssmp, const float* __restrict__ A_log,
             const float* __restrict__ Dp, const unsigned short* __restrict__ gate,
             const float* __restrict__ Sinit, unsigned short* __restrict__ y_bf) {
    const int tid = threadIdx.x;
    const int c = blockIdx.x & (NCH - 1);
    const int db = blockIdx.x >> 6;
    const int d = db * 256 + tid;
    const int t0 = c * CLEN;

    float Ac[16];
#pragma unroll
    for (int i = 0; i < 4; ++i) {
        float4 v = *(const float4*)&A_log[d * 16 + i * 4];
        Ac[i*4+0] = -__expf(v.x); Ac[i*4+1] = -__expf(v.y);
        Ac[i*4+2] = -__expf(v.z); Ac[i*4+3] = -__expf(v.w);
    }
    const float Dcoef = Dp[d];

    __shared__ float sB[CLEN][16], sC[CLEN][16];
    {
        int tt = tid >> 4, nn = tid & 15;
        sB[tt][nn] = ssmp[(t0 + tt) * 160 + 128 + nn];
        sC[tt][nn] = ssmp[(t0 + tt) * 160 + 144 + nn];
    }
    __syncthreads();

    float st[16];
    {
        const float* si = Sinit + ((size_t)c * 4096 + d) * 16;
#pragma unroll
        for (int i = 0; i < 4; ++i) {
            float4 v = *(const float4*)&si[i * 4];
            st[i*4] = v.x; st[i*4+1] = v.y; st[i*4+2] = v.z; st[i*4+3] = v.w;
        }
    }

    for (int tt = 0; tt < CLEN; ++tt) {
        size_t g = (size_t)(t0 + tt) * 4096 + d;
        float dtv = bf2f(dt[g]);
        float hcv = bf2f(hc[g]);
        float du = dtv * hcv;
        float p[16];
#pragma unroll
        for (int n = 0; n < 16; ++n) {
            float dA = __expf(dtv * Ac[n]);
            st[n] = fmaf(dA, st[n], du * sB[tt][n]);
            p[n] = st[n] * sC[tt][n];
        }
#pragma unroll
        for (int n = 0; n < 8; ++n) p[n] += p[n + 8];
#pragma unroll
        for (int n = 0; n < 4; ++n) p[n] += p[n + 4];
        p[0] += p[2]; p[1] += p[3];
        float csum = p[0] + p[1];
        float gv = bf2f(gate[g]);   // already silu'd
        float yv = (csum + hcv * Dcoef) * gv;
        y_bf[g] = f2bf(yv);
    }
}

// ---------------- launch ----------------
extern "C" void kernel_launch(void* const* d_in, const int* in_sizes, int n_in,
                              void* d_out, int out_size, void* d_ws, size_t ws_size,
                              hipStream_t stream) {
    (void)in_sizes; (void)n_in; (void)out_size; (void)ws_size;
    const float* hidden = (const float*)d_in[0];
    const float* W_in   = (const float*)d_in[1];
    const float* conv_w = (const float*)d_in[2];
    const float* conv_b = (const float*)d_in[3];
    const float* W_x    = (const float*)d_in[4];
    const float* W_dt   = (const float*)d_in[5];
    const float* b_dt   = (const float*)d_in[6];
    const float* A_log  = (const float*)d_in[7];
    const float* D_p    = (const float*)d_in[8];
    const float* W_out  = (const float*)d_in[9];
    float* out = (float*)d_out;

    char* w = (char*)d_ws;
    unsigned short* hid_bf = (unsigned short*)w;  w += (size_t)1024 * 2048 * 2;
    unsigned short* Wbig   = (unsigned short*)w;  w += (size_t)8192 * 2048 * 2;   // W_in
    unsigned short* Wout_bf= (unsigned short*)w;  w += (size_t)2048 * 4096 * 2;   // W_out
    unsigned short* h_bf   = (unsigned short*)w;  w += (size_t)1024 * 4096 * 2;
    unsigned short* gate_bf= (unsigned short*)w;  w += (size_t)1024 * 4096 * 2;
    // 32MB contiguous scratch: GEMM1 partials (2x16MB) and GEMM4 partials
    // (8x4MB); aliases hc_bf / dt_bf / Sbuf whose lifetimes don't overlap
    // (partials die at reduce2; hc/dt/Sbuf die at scan_p3 before GEMM4).
    unsigned short* pscr   = (unsigned short*)w;  w += (size_t)16 * 1024 * 1024 * 2;
    unsigned short* hc_bf  = pscr;                               // 8MB
    unsigned short* dt_bf  = pscr + (size_t)1024 * 4096;         // 8MB
    float* Sbuf            = (float*)(pscr + (size_t)2 * 1024 * 4096);  // 16MB
    float* ssmp            = (float*)w;           w += (size_t)1024 * 160 * 4;
    unsigned short* ts_bf  = (unsigned short*)w;  w += (size_t)1024 * 128 * 2;
    unsigned short* Wx_bf  = (unsigned short*)w;  w += (size_t)160 * 4096 * 2;
    unsigned short* Wdt_bf = (unsigned short*)w;  w += (size_t)4096 * 128 * 2;
    unsigned short* y_bf   = (unsigned short*)w;  w += (size_t)1024 * 4096 * 2;
    float* dtsum           = (float*)w;           w += (size_t)NCH * 4096 * 4;

    hipMemsetAsync(ssmp, 0, (size_t)1024 * 160 * 4, stream);   // GEMM2 atomic target

    // all f32->bf16 conversions in one launch
    cvt_all<<<4096, 256, 0, stream>>>(
        hidden, hid_bf, 1024 * 2048 / 4,
        W_in, Wbig, 8192 * 2048 / 4,
        W_x, Wx_bf, 160 * 4096 / 4,
        W_dt, Wdt_bf, 4096 * 128 / 4,
        W_out, Wout_bf, 2048 * 4096 / 4);

    // GEMM1: proj = hidden @ W_in^T (256^2, split-K x2, bf16 partials)
    gemm256p<<<dim3(128, 1, 2), 512, 0, stream>>>(
        (const short*)hid_bf, (const short*)Wbig, pscr, 8192, 2048, 1024);
    // fused reduce + split: h bf16 | silu(gate) bf16
    reduce2<<<2048, 256, 0, stream>>>(pscr, h_bf, gate_bf);

    conv_silu<<<16384, 256, 0, stream>>>(h_bf, conv_w, conv_b, hc_bf);

    gemm_bt<128, EPI_ATOMIC><<<dim3(2, 8, 16), 256, 0, stream>>>(
        (const short*)hc_bf, (const short*)Wx_bf, ssmp, nullptr, nullptr,
        1024, 160, 4096, 160, 256);

    cvt_ts<<<128, 256, 0, stream>>>(ssmp, ts_bf);

    // GEMM3: dt = softplus(ts @ W_dt^T + b_dt) -> bf16
    gemm_bt<128, EPI_SOFTPLUS><<<dim3(32, 8, 1), 256, 0, stream>>>(
        (const short*)ts_bf, (const short*)Wdt_bf, (float*)dt_bf, nullptr, b_dt,
        1024, 4096, 128, 4096, 128);

    scan_p1<<<NCH * 16, 256, 0, stream>>>(dt_bf, hc_bf, ssmp, A_log, Sbuf, dtsum);
    scan_p2<<<256, 256, 0, stream>>>(A_log, dtsum, Sbuf);
    scan_p3<<<NCH * 16, 256, 0, stream>>>(dt_bf, hc_bf, ssmp, A_log, D_p, gate_bf, Sbuf, y_bf);

    // GEMM4: out = y @ W_out^T (256^2, split-K x8, bf16 partials) + reduce
    gemm256p<<<dim3(32, 1, 8), 512, 0, stream>>>(
        (const short*)y_bf, (const short*)Wout_bf, pscr, 2048, 4096, 512);
    reduce8<<<2048, 256, 0, stream>>>(pscr, out);
}

// Round 13
// 220.374 us; speedup vs baseline: 1.1297x; 1.1297x over previous
//
#include <hip/hip_runtime.h>
#include <math.h>

#define AS1 __attribute__((address_space(1)))
#define AS3 __attribute__((address_space(3)))

typedef __attribute__((ext_vector_type(8))) short short8;
typedef __attribute__((ext_vector_type(8))) unsigned short ushort8_t;
typedef __attribute__((ext_vector_type(4))) float f32x4;

#define WAITV(n) asm volatile("s_waitcnt vmcnt(" #n ")" ::: "memory")
#define LGKM0()  asm volatile("s_waitcnt lgkmcnt(0)" ::: "memory")
#define BARRIER() asm volatile("s_barrier" ::: "memory")

static __device__ __forceinline__ unsigned short f2bf(float f) {
    unsigned u = __float_as_uint(f);
    unsigned r = (u + 0x7fffu + ((u >> 16) & 1u)) >> 16;
    return (unsigned short)r;
}
static __device__ __forceinline__ float bf2f(unsigned short u) {
    return __uint_as_float(((unsigned)u) << 16);
}

// ---------------- fused f32 -> bf16 convert for all 5 tensors ----------------
__global__ __launch_bounds__(256)
void cvt_all(const float* __restrict__ s0, unsigned short* __restrict__ d0, int n0,
             const float* __restrict__ s1, unsigned short* __restrict__ d1, int n1,
             const float* __restrict__ s2, unsigned short* __restrict__ d2, int n2,
             const float* __restrict__ s3, unsigned short* __restrict__ d3, int n3,
             const float* __restrict__ s4, unsigned short* __restrict__ d4, int n4c) {
    int i = blockIdx.x * 256 + threadIdx.x;
    int stride = gridDim.x * 256;
    int t01 = n0 + n1, t02 = t01 + n2, t03 = t02 + n3, tot = t03 + n4c;
    for (; i < tot; i += stride) {
        const float* s; unsigned short* d; int j;
        if (i < n0)      { s = s0; d = d0; j = i; }
        else if (i < t01){ s = s1; d = d1; j = i - n0; }
        else if (i < t02){ s = s2; d = d2; j = i - t01; }
        else if (i < t03){ s = s3; d = d3; j = i - t02; }
        else             { s = s4; d = d4; j = i - t03; }
        float4 v = ((const float4*)s)[j];
        ushort4 o;
        o.x = f2bf(v.x); o.y = f2bf(v.y); o.z = f2bf(v.z); o.w = f2bf(v.w);
        ((ushort4*)d)[j] = o;
    }
}

// extract ts (cols 0..127 of ssm_p, row stride 160) -> dense bf16 1024x128
__global__ __launch_bounds__(256) void cvt_ts(const float* __restrict__ ssmp,
                                              unsigned short* __restrict__ ts) {
    int i = blockIdx.x * 256 + threadIdx.x;   // < 32768
    int t = i >> 5, c4 = (i & 31) * 4;
    float4 v = *(const float4*)&ssmp[t * 160 + c4];
    ushort4 o;
    o.x = f2bf(v.x); o.y = f2bf(v.y); o.z = f2bf(v.z); o.w = f2bf(v.w);
    *(ushort4*)&ts[t * 128 + c4] = o;
}

// ------- depthwise causal conv (K=4, bf16 in) + bias + silu -> hc bf16 -------
__global__ __launch_bounds__(256) void conv_silu(const unsigned short* __restrict__ h,
                                                 const float* __restrict__ cw,
                                                 const float* __restrict__ cb,
                                                 unsigned short* __restrict__ hc_bf) {
    int idx = blockIdx.x * 256 + threadIdx.x;   // < 1024*4096
    int d = idx & 4095, t = idx >> 12;
    float acc = cb[d];
    float4 w = *(const float4*)&cw[d * 4];
    const float* wp = (const float*)&w;
#pragma unroll
    for (int k = 0; k < 4; ++k) {
        int tt = t + k - 3;
        if (tt >= 0) acc += bf2f(h[tt * 4096 + d]) * wp[k];
    }
    float s = acc / (1.f + __expf(-acc));   // silu
    hc_bf[idx] = f2bf(s);
}

// ---- reduce 2 bf16 split-K partials (1024x8192) -> h bf16 | silu(gate) bf16 ----
__global__ __launch_bounds__(256) void reduce2(const unsigned short* __restrict__ P,
                                               unsigned short* __restrict__ h_bf,
                                               unsigned short* __restrict__ gate_bf) {
    const int NCHK = 1024 * 8192 / 8;
    int i = blockIdx.x * 256 + threadIdx.x;
    int stride = gridDim.x * 256;
    for (; i < NCHK; i += stride) {
        ushort8_t a = ((const ushort8_t*)P)[i];
        ushort8_t b = ((const ushort8_t*)P)[i + NCHK];
        int e0 = i * 8;
        int row = e0 >> 13, col = e0 & 8191;
        ushort8_t o;
        if (col < 4096) {
#pragma unroll
            for (int j = 0; j < 8; ++j) o[j] = f2bf(bf2f(a[j]) + bf2f(b[j]));
            ((ushort8_t*)h_bf)[(row * 4096 + col) >> 3] = o;
        } else {
#pragma unroll
            for (int j = 0; j < 8; ++j) {
                float v = bf2f(a[j]) + bf2f(b[j]);
                o[j] = f2bf(v / (1.f + __expf(-v)));
            }
            ((ushort8_t*)gate_bf)[(row * 4096 + (col - 4096)) >> 3] = o;
        }
    }
}

// ---- reduce 8 bf16 split-K partials (1024x2048 each) -> f32 out ----
__global__ __launch_bounds__(256) void reduce8(const unsigned short* __restrict__ P,
                                               float* __restrict__ out) {
    const int NCHK = 1024 * 2048 / 4;
    int i = blockIdx.x * 256 + threadIdx.x;
    int stride = gridDim.x * 256;
    for (; i < NCHK; i += stride) {
        float4 s = make_float4(0.f, 0.f, 0.f, 0.f);
#pragma unroll
        for (int z = 0; z < 8; ++z) {
            ushort4 v = ((const ushort4*)(P + (size_t)z * 1024 * 2048))[i];
            s.x += bf2f(v.x); s.y += bf2f(v.y); s.z += bf2f(v.z); s.w += bf2f(v.w);
        }
        ((float4*)out)[i] = s;
    }
}

// ======== m201-style 8-phase 256x256 bf16 MFMA GEMM: C = A @ B^T ========
// BM=BN=256, BK=64. 512 thr = 8 waves (2M x 4N), wave tile 128x64.
// LDS = 4 half-buffers H0..H3 (32KB each = 128KB); half = one ks-plane pair
// {A [256][32] + B [256][32]}. Tile u occupies (H[2u&3] = ks0, H[(2u+1)&3] =
// ks1). 4 phases per tile, 16 MFMA each: (mh0,ks0),(mh1,ks0),(mh0,ks1),
// (mh1,ks1). Each phase stages ONE plane (2 gloads) into a half-buffer that
// died >=1 barrier ago: ph1/ph2 stage (u+1)'s ks1; ph3/ph4 stage (u+2)'s
// ks0 (into Ha, dead after ph2). Staging is UNCONDITIONAL (beyond-NT tiles
// read in-bounds ws garbage, never consumed) so vmcnt is uniform: WAITV(8)
// at each half-switch = 2 halves (8 loads) in flight. Slot-XOR swizzle
// (round-11, conflicts=0) on both sides (rule 21). 1 barrier/phase + 1 at
// half-switches. setprio around MFMA. XCD-bijective block swizzle.
// Split-K bf16 partials -> reduce2 / reduce8. M fixed = 1024.
__global__ __launch_bounds__(512, 2)
void gemm256k(const short* __restrict__ A, const short* __restrict__ B,
              unsigned short* __restrict__ Pbase,
              int N, int K, int kchunk) {
    __shared__ short lds[65536];   // H0..H3, 16384 shorts each (A plane + B plane)

    const int tid = threadIdx.x;
    const int wv = tid >> 6, ln = tid & 63;
    const int lr = ln & 15, kg = ln >> 4;
    const int wm = wv >> 2, wn = wv & 3;      // 2M x 4N

    const int nwg = gridDim.x;                 // multiple of 8
    const int bid = blockIdx.x;
    const int swz = (bid & 7) * (nwg >> 3) + (bid >> 3);
    const int by = swz & 3, bx = swz >> 2;     // M/256 = 4 always
    const int m0 = by * 256, n0 = bx * 256;
    const int kbeg = blockIdx.z * kchunk;
    const int NT = kchunk >> 6;                // BK = 64 (NT = 16 or 8, even)

    f32x4 acc[8][4];
#pragma unroll
    for (int mi = 0; mi < 8; ++mi)
#pragma unroll
        for (int ni = 0; ni < 4; ++ni) acc[mi][ni] = (f32x4){0.f, 0.f, 0.f, 0.f};

    // staging: pass p covers rows p*128..p*128+127; 4 slots of 16B per
    // 32-elem plane row; source slot pre-swizzled (same involution as reads)
    const int sr = tid >> 2;                  // row within pass
    const int sl = tid & 3;
    const int ssw = sl ^ ((sr >> 1) & 3);     // (row>>1)&3 identical for p=0,1
    const short* gA = A + (size_t)(m0 + sr) * K + kbeg + ssw * 8;
    const short* gB = B + (size_t)(n0 + sr) * K + kbeg + ssw * 8;
    const size_t rK128 = (size_t)128 * K;

    // fragment read offsets (shorts), incl. swizzle XOR
    int offA[8], offB[4];
#pragma unroll
    for (int mi = 0; mi < 8; ++mi) {
        int row = wm * 128 + mi * 16 + lr;
        offA[mi] = row * 32 + (kg ^ ((row >> 1) & 3)) * 8;
    }
#pragma unroll
    for (int ni = 0; ni < 4; ++ni) {
        int row = wn * 64 + ni * 16 + lr;
        offB[ni] = 8192 + row * 32 + (kg ^ ((row >> 1) & 3)) * 8;
    }

#define STG_A(Hi, koff)                                                       \
    { __builtin_amdgcn_global_load_lds((const AS1 void*)(gA + (koff)),        \
          (AS3 void*)(lds + (Hi) * 16384 + wv * 512), 16, 0, 0);              \
      __builtin_amdgcn_global_load_lds((const AS1 void*)(gA + rK128 + (koff)),\
          (AS3 void*)(lds + (Hi) * 16384 + 4096 + wv * 512), 16, 0, 0); }
#define STG_B(Hi, koff)                                                       \
    { __builtin_amdgcn_global_load_lds((const AS1 void*)(gB + (koff)),        \
          (AS3 void*)(lds + (Hi) * 16384 + 8192 + wv * 512), 16, 0, 0);       \
      __builtin_amdgcn_global_load_lds((const AS1 void*)(gB + rK128 + (koff)),\
          (AS3 void*)(lds + (Hi) * 16384 + 8192 + 4096 + wv * 512), 16, 0, 0); }
#define MFMA4(mi, a)                                                          \
    acc[mi][0] = __builtin_amdgcn_mfma_f32_16x16x32_bf16(a, vb0, acc[mi][0], 0, 0, 0); \
    acc[mi][1] = __builtin_amdgcn_mfma_f32_16x16x32_bf16(a, vb1, acc[mi][1], 0, 0, 0); \
    acc[mi][2] = __builtin_amdgcn_mfma_f32_16x16x32_bf16(a, vb2, acc[mi][2], 0, 0, 0); \
    acc[mi][3] = __builtin_amdgcn_mfma_f32_16x16x32_bf16(a, vb3, acc[mi][3], 0, 0, 0);

// one K-tile u in halves (HA=ks0, HB=ks1); stages into HN1 ((u+1) ks1) and HA
#define TILE(HA, HB, HN1, u)                                                  \
    {                                                                         \
        const int kN1 = ((u) + 1) * 64 + 32;                                  \
        const int kN2 = ((u) + 2) * 64;                                       \
        const short* ha = lds + (HA) * 16384;                                 \
        const short* hb = lds + (HB) * 16384;                                 \
        short8 vb0, vb1, vb2, vb3, a0, a1, a2, a3;                            \
        /* ph1: mh0, ks0 */                                                   \
        WAITV(8);                                                             \
        BARRIER();                                                            \
        vb0 = *(const short8*)(ha + offB[0]);                                 \
        vb1 = *(const short8*)(ha + offB[1]);                                 \
        vb2 = *(const short8*)(ha + offB[2]);                                 \
        vb3 = *(const short8*)(ha + offB[3]);                                 \
        a0 = *(const short8*)(ha + offA[0]);                                  \
        a1 = *(const short8*)(ha + offA[1]);                                  \
        a2 = *(const short8*)(ha + offA[2]);                                  \
        a3 = *(const short8*)(ha + offA[3]);                                  \
        STG_A(HN1, kN1);                                                      \
        BARRIER();                                                            \
        LGKM0();                                                              \
        __builtin_amdgcn_s_setprio(1);                                        \
        MFMA4(0, a0); MFMA4(1, a1); MFMA4(2, a2); MFMA4(3, a3);               \
        __builtin_amdgcn_s_setprio(0);                                        \
        /* ph2: mh1, ks0 */                                                   \
        a0 = *(const short8*)(ha + offA[4]);                                  \
        a1 = *(const short8*)(ha + offA[5]);                                  \
        a2 = *(const short8*)(ha + offA[6]);                                  \
        a3 = *(const short8*)(ha + offA[7]);                                  \
        STG_B(HN1, kN1);                                                      \
        BARRIER();                                                            \
        LGKM0();                                                              \
        __builtin_amdgcn_s_setprio(1);                                        \
        MFMA4(4, a0); MFMA4(5, a1); MFMA4(6, a2); MFMA4(7, a3);               \
        __builtin_amdgcn_s_setprio(0);                                        \
        /* ph3: mh0, ks1 — stages (u+2) ks0 into HA (dead since ph2 bar) */   \
        WAITV(8);                                                             \
        BARRIER();                                                            \
        vb0 = *(const short8*)(hb + offB[0]);                                 \
        vb1 = *(const short8*)(hb + offB[1]);                                 \
        vb2 = *(const short8*)(hb + offB[2]);                                 \
        vb3 = *(const short8*)(hb + offB[3]);                                 \
        a0 = *(const short8*)(hb + offA[0]);                                  \
        a1 = *(const short8*)(hb + offA[1]);                                  \
        a2 = *(const short8*)(hb + offA[2]);                                  \
        a3 = *(const short8*)(hb + offA[3]);                                  \
        STG_A(HA, kN2);                                                       \
        BARRIER();                                                            \
        LGKM0();                                                              \
        __builtin_amdgcn_s_setprio(1);                                        \
        MFMA4(0, a0); MFMA4(1, a1); MFMA4(2, a2); MFMA4(3, a3);               \
        __builtin_amdgcn_s_setprio(0);                                        \
        /* ph4: mh1, ks1 */                                                   \
        a0 = *(const short8*)(hb + offA[4]);                                  \
        a1 = *(const short8*)(hb + offA[5]);                                  \
        a2 = *(const short8*)(hb + offA[6]);                                  \
        a3 = *(const short8*)(hb + offA[7]);                                  \
        STG_B(HA, kN2);                                                       \
        BARRIER();                                                            \
        LGKM0();                                                              \
        __builtin_amdgcn_s_setprio(1);                                        \
        MFMA4(4, a0); MFMA4(5, a1); MFMA4(6, a2); MFMA4(7, a3);               \
        __builtin_amdgcn_s_setprio(0);                                        \
    }

    // prologue: stage tile 0 (H0,H1) and tile 1 (H2,H3) fully — 16 loads
    STG_A(0, 0);  STG_B(0, 0);    // t0 ks0
    STG_A(1, 32); STG_B(1, 32);   // t0 ks1
    STG_A(2, 64); STG_B(2, 64);   // t1 ks0
    STG_A(3, 96); STG_B(3, 96);   // t1 ks1

    for (int u = 0; u < NT; u += 2) {
        TILE(0, 1, 3, u);       // even tile: ks0=H0, ks1=H1; stages (u+1)ks1->H3
        TILE(2, 3, 1, u + 1);   // odd tile:  ks0=H2, ks1=H3; stages (u+2)ks1->H1
    }
#undef STG_A
#undef STG_B
#undef MFMA4
#undef TILE

    // epilogue: bf16 split-K partial, region z = blockIdx.z
    unsigned short* P = Pbase + (size_t)blockIdx.z * 1024 * N;
#pragma unroll
    for (int mi = 0; mi < 8; ++mi) {
        int crow0 = m0 + wm * 128 + mi * 16 + kg * 4;
#pragma unroll
        for (int ni = 0; ni < 4; ++ni) {
            int ccol = n0 + wn * 64 + ni * 16 + lr;
#pragma unroll
            for (int i = 0; i < 4; ++i)
                P[(size_t)(crow0 + i) * N + ccol] = f2bf(acc[mi][ni][i]);
        }
    }
}

// ---------------- 2-phase bf16 MFMA GEMM (GEMM2/3) ----------------
enum { EPI_PLAIN = 0, EPI_SPLIT = 1, EPI_ATOMIC = 2, EPI_SOFTPLUS = 3 };

template <int BM, int EPI>
__global__ __launch_bounds__(256)
void gemm_bt(const short* __restrict__ A, const short* __restrict__ B,
             float* __restrict__ C, float* __restrict__ C2,
             const float* __restrict__ bias,
             int M, int N, int K, int ldc, int kcLen) {
    __shared__ short A_lds[BM * 32];
    __shared__ short B_lds[128 * 32];
    const int tid = threadIdx.x;
    const int wv = tid >> 6, ln = tid & 63;
    const int lr = ln & 15, kg = ln >> 4;
    const int m0 = blockIdx.y * BM;
    const int n0 = blockIdx.x * 128;
    const int kbeg = blockIdx.z * kcLen;
    const int kend = kbeg + kcLen;
    const int wm = wv >> 1, wn = wv & 1;
    constexpr int MR = BM / 32;

    f32x4 acc[MR][4];
#pragma unroll
    for (int mi = 0; mi < MR; ++mi)
#pragma unroll
        for (int ni = 0; ni < 4; ++ni) acc[mi][ni] = (f32x4){0.f, 0.f, 0.f, 0.f};

    const int arow = tid >> 2;
    const int kq8 = (tid & 3) * 8;

    for (int k0 = kbeg; k0 < kend; k0 += 32) {
#pragma unroll
        for (int r = 0; r < BM / 64; ++r) {
            const short* srcA = A + (size_t)(m0 + r * 64 + arow) * K + (k0 + kq8);
            short* dstA = &A_lds[(r * 64 + wv * 16) * 32];
            __builtin_amdgcn_global_load_lds((const AS1 void*)srcA, (AS3 void*)dstA, 16, 0, 0);
        }
#pragma unroll
        for (int r = 0; r < 2; ++r) {
            int brow = n0 + r * 64 + arow;
            if (brow > N - 1) brow = N - 1;
            const short* srcB = B + (size_t)brow * K + (k0 + kq8);
            short* dstB = &B_lds[(r * 64 + wv * 16) * 32];
            __builtin_amdgcn_global_load_lds((const AS1 void*)srcB, (AS3 void*)dstB, 16, 0, 0);
        }
        __syncthreads();

        short8 av[MR], bv[4];
#pragma unroll
        for (int mi = 0; mi < MR; ++mi)
            av[mi] = *(const short8*)&A_lds[(wm * (BM / 2) + mi * 16 + lr) * 32 + kg * 8];
#pragma unroll
        for (int ni = 0; ni < 4; ++ni)
            bv[ni] = *(const short8*)&B_lds[(wn * 64 + ni * 16 + lr) * 32 + kg * 8];
#pragma unroll
        for (int mi = 0; mi < MR; ++mi)
#pragma unroll
            for (int ni = 0; ni < 4; ++ni)
                acc[mi][ni] = __builtin_amdgcn_mfma_f32_16x16x32_bf16(av[mi], bv[ni], acc[mi][ni], 0, 0, 0);
        __syncthreads();
    }

#pragma unroll
    for (int mi = 0; mi < MR; ++mi) {
        int crow0 = m0 + wm * (BM / 2) + mi * 16 + kg * 4;
#pragma unroll
        for (int ni = 0; ni < 4; ++ni) {
            int ccol = n0 + wn * 64 + ni * 16 + lr;
#pragma unroll
            for (int i = 0; i < 4; ++i) {
                float v = acc[mi][ni][i];
                size_t crow = (size_t)(crow0 + i);
                if constexpr (EPI == EPI_PLAIN) {
                    C[crow * ldc + ccol] = v;
                } else if constexpr (EPI == EPI_SPLIT) {
                    if (ccol < 4096) C[crow * 4096 + ccol] = v;
                    else C2[crow * 4096 + (ccol - 4096)] = v;
                } else if constexpr (EPI == EPI_ATOMIC) {
                    if (ccol < N) atomicAdd(&C[crow * ldc + ccol], v);
                } else {   // EPI_SOFTPLUS: bf16 softplus(v + bias[n]) -> dt
                    float x = v + bias[ccol];
                    float sp = fmaxf(x, 0.f) + log1pf(__expf(-fabsf(x)));
                    ((unsigned short*)C)[crow * ldc + ccol] = f2bf(sp);
                }
            }
        }
    }
}

// ================= chunked selective scan (bf16 dt/hc/gate) =================
#define CLEN 16
#define NCH 64

__global__ __launch_bounds__(256)
void scan_p1(const unsigned short* __restrict__ dt, const unsigned short* __restrict__ hc,
             const float* __restrict__ ssmp, const float* __restrict__ A_log,
             float* __restrict__ Sbuf, float* __restrict__ dtsum) {
    const int tid = threadIdx.x;
    const int c = blockIdx.x & (NCH - 1);
    const int db = blockIdx.x >> 6;
    const int d = db * 256 + tid;
    const int t0 = c * CLEN;

    float Ac[16];
#pragma unroll
    for (int i = 0; i < 4; ++i) {
        float4 v = *(const float4*)&A_log[d * 16 + i * 4];
        Ac[i*4+0] = -__expf(v.x); Ac[i*4+1] = -__expf(v.y);
        Ac[i*4+2] = -__expf(v.z); Ac[i*4+3] = -__expf(v.w);
    }

    __shared__ float sB[CLEN][16];
    sB[tid >> 4][tid & 15] = ssmp[(t0 + (tid >> 4)) * 160 + 128 + (tid & 15)];
    __syncthreads();

    float st[16];
#pragma unroll
    for (int n = 0; n < 16; ++n) st[n] = 0.f;
    float ds = 0.f;

    for (int tt = 0; tt < CLEN; ++tt) {
        size_t g = (size_t)(t0 + tt) * 4096 + d;
        float dtv = bf2f(dt[g]);
        float hcv = bf2f(hc[g]);
        float du = dtv * hcv;
        ds += dtv;
#pragma unroll
        for (int n = 0; n < 16; ++n) {
            float dA = __expf(dtv * Ac[n]);
            st[n] = fmaf(dA, st[n], du * sB[tt][n]);
        }
    }

    float* o = Sbuf + ((size_t)c * 4096 + d) * 16;
#pragma unroll
    for (int i = 0; i < 4; ++i)
        *(float4*)&o[i * 4] = make_float4(st[i*4], st[i*4+1], st[i*4+2], st[i*4+3]);
    dtsum[c * 4096 + d] = ds;
}

__global__ __launch_bounds__(256)
void scan_p2(const float* __restrict__ A_log, const float* __restrict__ dtsum,
             float* __restrict__ S) {
    const int idx = blockIdx.x * 256 + threadIdx.x;   // (d,n), 65536
    const int d = idx >> 4;
    const float Ac = -__expf(A_log[idx]);

    float sl[NCH], Pv[NCH];
#pragma unroll
    for (int c = 0; c < NCH; ++c) sl[c] = S[(size_t)c * 65536 + idx];
#pragma unroll
    for (int c = 0; c < NCH; ++c) Pv[c] = __expf(Ac * dtsum[c * 4096 + d]);

    float s = 0.f;
#pragma unroll
    for (int c = 0; c < NCH; ++c) {
        S[(size_t)c * 65536 + idx] = s;
        s = fmaf(Pv[c], s, sl[c]);
    }
}

__global__ __launch_bounds__(256)
void scan_p3(const unsigned short* __restrict__ dt, const unsigned short* __restrict__ hc,
             const float* __restrict__ ssmp, const float* __restrict__ A_log,
             const float* __restrict__ Dp, const unsigned short* __restrict__ gate,
             const float* __restrict__ Sinit, unsigned short* __restrict__ y_bf) {
    const int tid = threadIdx.x;
    const int c = blockIdx.x & (NCH - 1);
    const int db = blockIdx.x >> 6;
    const int d = db * 256 + tid;
    const int t0 = c * CLEN;

    float Ac[16];
#pragma unroll
    for (int i = 0; i < 4; ++i) {
        float4 v = *(const float4*)&A_log[d * 16 + i * 4];
        Ac[i*4+0] = -__expf(v.x); Ac[i*4+1] = -__expf(v.y);
        Ac[i*4+2] = -__expf(v.z); Ac[i*4+3] = -__expf(v.w);
    }
    const float Dcoef = Dp[d];

    __shared__ float sB[CLEN][16], sC[CLEN][16];
    {
        int tt = tid >> 4, nn = tid & 15;
        sB[tt][nn] = ssmp[(t0 + tt) * 160 + 128 + nn];
        sC[tt][nn] = ssmp[(t0 + tt) * 160 + 144 + nn];
    }
    __syncthreads();

    float st[16];
    {
        const float* si = Sinit + ((size_t)c * 4096 + d) * 16;
#pragma unroll
        for (int i = 0; i < 4; ++i) {
            float4 v = *(const float4*)&si[i * 4];
            st[i*4] = v.x; st[i*4+1] = v.y; st[i*4+2] = v.z; st[i*4+3] = v.w;
        }
    }

    for (int tt = 0; tt < CLEN; ++tt) {
        size_t g = (size_t)(t0 + tt) * 4096 + d;
        float dtv = bf2f(dt[g]);
        float hcv = bf2f(hc[g]);
        float du = dtv * hcv;
        float p[16];
#pragma unroll
        for (int n = 0; n < 16; ++n) {
            float dA = __expf(dtv * Ac[n]);
            st[n] = fmaf(dA, st[n], du * sB[tt][n]);
            p[n] = st[n] * sC[tt][n];
        }
#pragma unroll
        for (int n = 0; n < 8; ++n) p[n] += p[n + 8];
#pragma unroll
        for (int n = 0; n < 4; ++n) p[n] += p[n + 4];
        p[0] += p[2]; p[1] += p[3];
        float csum = p[0] + p[1];
        float gv = bf2f(gate[g]);   // already silu'd
        float yv = (csum + hcv * Dcoef) * gv;
        y_bf[g] = f2bf(yv);
    }
}

// ---------------- launch ----------------
extern "C" void kernel_launch(void* const* d_in, const int* in_sizes, int n_in,
                              void* d_out, int out_size, void* d_ws, size_t ws_size,
                              hipStream_t stream) {
    (void)in_sizes; (void)n_in; (void)out_size; (void)ws_size;
    const float* hidden = (const float*)d_in[0];
    const float* W_in   = (const float*)d_in[1];
    const float* conv_w = (const float*)d_in[2];
    const float* conv_b = (const float*)d_in[3];
    const float* W_x    = (const float*)d_in[4];
    const float* W_dt   = (const float*)d_in[5];
    const float* b_dt   = (const float*)d_in[6];
    const float* A_log  = (const float*)d_in[7];
    const float* D_p    = (const float*)d_in[8];
    const float* W_out  = (const float*)d_in[9];
    float* out = (float*)d_out;

    char* w = (char*)d_ws;
    unsigned short* hid_bf = (unsigned short*)w;  w += (size_t)1024 * 2048 * 2;
    unsigned short* Wbig   = (unsigned short*)w;  w += (size_t)8192 * 2048 * 2;   // W_in
    unsigned short* Wout_bf= (unsigned short*)w;  w += (size_t)2048 * 4096 * 2;   // W_out
    unsigned short* h_bf   = (unsigned short*)w;  w += (size_t)1024 * 4096 * 2;
    unsigned short* gate_bf= (unsigned short*)w;  w += (size_t)1024 * 4096 * 2;
    // 32MB contiguous scratch: GEMM1 partials (2x16MB) and GEMM4 partials
    // (8x4MB); aliases hc_bf / dt_bf / Sbuf whose lifetimes don't overlap
    // (partials die at reduce2; hc/dt/Sbuf die at scan_p3 before GEMM4).
    unsigned short* pscr   = (unsigned short*)w;  w += (size_t)16 * 1024 * 1024 * 2;
    unsigned short* hc_bf  = pscr;                               // 8MB
    unsigned short* dt_bf  = pscr + (size_t)1024 * 4096;         // 8MB
    float* Sbuf            = (float*)(pscr + (size_t)2 * 1024 * 4096);  // 16MB
    float* ssmp            = (float*)w;           w += (size_t)1024 * 160 * 4;
    unsigned short* ts_bf  = (unsigned short*)w;  w += (size_t)1024 * 128 * 2;
    unsigned short* Wx_bf  = (unsigned short*)w;  w += (size_t)160 * 4096 * 2;
    unsigned short* Wdt_bf = (unsigned short*)w;  w += (size_t)4096 * 128 * 2;
    unsigned short* y_bf   = (unsigned short*)w;  w += (size_t)1024 * 4096 * 2;
    float* dtsum           = (float*)w;           w += (size_t)NCH * 4096 * 4;

    hipMemsetAsync(ssmp, 0, (size_t)1024 * 160 * 4, stream);   // GEMM2 atomic target

    // all f32->bf16 conversions in one launch
    cvt_all<<<4096, 256, 0, stream>>>(
        hidden, hid_bf, 1024 * 2048 / 4,
        W_in, Wbig, 8192 * 2048 / 4,
        W_x, Wx_bf, 160 * 4096 / 4,
        W_dt, Wdt_bf, 4096 * 128 / 4,
        W_out, Wout_bf, 2048 * 4096 / 4);

    // GEMM1: proj = hidden @ W_in^T (256^2 8-phase, split-K x2, bf16 partials)
    gemm256k<<<dim3(128, 1, 2), 512, 0, stream>>>(
        (const short*)hid_bf, (const short*)Wbig, pscr, 8192, 2048, 1024);
    // fused reduce + split: h bf16 | silu(gate) bf16
    reduce2<<<2048, 256, 0, stream>>>(pscr, h_bf, gate_bf);

    conv_silu<<<16384, 256, 0, stream>>>(h_bf, conv_w, conv_b, hc_bf);

    gemm_bt<128, EPI_ATOMIC><<<dim3(2, 8, 16), 256, 0, stream>>>(
        (const short*)hc_bf, (const short*)Wx_bf, ssmp, nullptr, nullptr,
        1024, 160, 4096, 160, 256);

    cvt_ts<<<128, 256, 0, stream>>>(ssmp, ts_bf);

    // GEMM3: dt = softplus(ts @ W_dt^T + b_dt) -> bf16
    gemm_bt<128, EPI_SOFTPLUS><<<dim3(32, 8, 1), 256, 0, stream>>>(
        (const short*)ts_bf, (const short*)Wdt_bf, (float*)dt_bf, nullptr, b_dt,
        1024, 4096, 128, 4096, 128);

    scan_p1<<<NCH * 16, 256, 0, stream>>>(dt_bf, hc_bf, ssmp, A_log, Sbuf, dtsum);
    scan_p2<<<256, 256, 0, stream>>>(A_log, dtsum, Sbuf);
    scan_p3<<<NCH * 16, 256, 0, stream>>>(dt_bf, hc_bf, ssmp, A_log, D_p, gate_bf, Sbuf, y_bf);

    // GEMM4: out = y @ W_out^T (256^2 8-phase, split-K x8, bf16 partials)
    gemm256k<<<dim3(32, 1, 8), 512, 0, stream>>>(
        (const short*)y_bf, (const short*)Wout_bf, pscr, 2048, 4096, 512);
    reduce8<<<2048, 256, 0, stream>>>(pscr, out);
}